// Round 13
// baseline (386.568 us; speedup 1.0000x reference)
//
#include <hip/hip_runtime.h>
#include <hip/hip_fp16.h>
#include <math.h>

// ---------------- problem constants ----------------
#define ND 2048
#define NS 1024
#define DIN 768
#define DOUT 64
#define NSTEPS 20
static constexpr float BLUR2 = 0.05f * 0.05f; // blur^p, p=2

// ---------------- ws layout ----------------
// float offsets:
#define OFF_X     0u              // 3072*64 = 196608
#define OFF_MM    199680u         // 128 uints: 64 min keys | 64 max keys
#define OFF_POTS  199808u         // 23 gens x 6144 floats (TILDE potentials p~ = p - n)
                                  // gen0 = zpot (-n), gen1 = init, gen2..21 = steps,
                                  // gen22 = final. per gen:
                                  // [f_ab 2048 | g_ab 1024 | f_aa 2048 | g_bb 1024]
#define POT_STRIDE 6144u
#define OFF_BARRIER 341120u       // 2048 uints: 32 arrival lines x 64-uint stride
// half offsets (element index into (__half*)ws): fp16 dot matrices
#define H_DXY 694528u             // 2048x1024
#define H_DYX 2791680u            // 1024x2048 (transpose)
#define H_DXX 4888832u            // 2048x2048
#define H_DYY 9083136u            // 1024x1024

// 1152 blocks = 4.5 blocks/CU; __launch_bounds__(256,6) caps VGPR so HW capacity is
// 6 blocks/CU > 4.5 needed: co-residency margin for the device-wide barrier.
#define NBLK 1152

// monotone float<->uint key encoding (order-preserving for atomicMin/Max)
__device__ inline unsigned fkey(float f) {
  const unsigned b = __float_as_uint(f);
  return (b & 0x80000000u) ? ~b : (b | 0x80000000u);
}
__device__ inline float funkey(unsigned k) {
  const unsigned b = (k & 0x80000000u) ? (k & 0x7FFFFFFFu) : ~k;
  return __uint_as_float(b);
}

// ---------------- kernel 0: seed min/max keys + zero barrier area ----------------
__global__ __launch_bounds__(256) void init_mm(float* __restrict__ ws) {
  const int t = threadIdx.x;
  unsigned* mm = reinterpret_cast<unsigned*>(ws + OFF_MM);
  if (t < 64)       mm[t] = 0xFFFFFFFFu;
  else if (t < 128) mm[t] = 0u;
  unsigned* bar = reinterpret_cast<unsigned*>(ws + OFF_BARRIER);
  for (int i = t; i < 2048; i += 256) bar[i] = 0u;
}

// ---------------- kernel 1: projection (K-split) + zpot + atomic min/max ----------
__global__ __launch_bounds__(256) void proj_kernel(const float* __restrict__ d,
                                                   const float* __restrict__ s,
                                                   const float* __restrict__ M,
                                                   float* __restrict__ ws) {
  const int w    = threadIdx.x >> 6;
  const int lane = threadIdx.x & 63;
  const int r0   = blockIdx.x * 4;

  const float* base;
  if (r0 < ND) base = d + (size_t)r0 * DIN;
  else         base = s + (size_t)(r0 - ND) * DIN;

  const float4* s0 = reinterpret_cast<const float4*>(base + 0 * DIN + w * 192);
  const float4* s1 = reinterpret_cast<const float4*>(base + 1 * DIN + w * 192);
  const float4* s2 = reinterpret_cast<const float4*>(base + 2 * DIN + w * 192);
  const float4* s3 = reinterpret_cast<const float4*>(base + 3 * DIN + w * 192);
  const float* Mw = M + (size_t)(w * 192) * DOUT + lane;

  float a0 = 0.f, a1 = 0.f, a2 = 0.f, a3 = 0.f;
#pragma unroll 4
  for (int kk = 0; kk < 48; ++kk) {
    const float4 r0v = s0[kk];
    const float4 r1v = s1[kk];
    const float4 r2v = s2[kk];
    const float4 r3v = s3[kk];
    const float m0 = Mw[(kk * 4 + 0) * DOUT];
    const float m1 = Mw[(kk * 4 + 1) * DOUT];
    const float m2 = Mw[(kk * 4 + 2) * DOUT];
    const float m3 = Mw[(kk * 4 + 3) * DOUT];
    a0 = fmaf(r0v.x, m0, a0); a0 = fmaf(r0v.y, m1, a0);
    a0 = fmaf(r0v.z, m2, a0); a0 = fmaf(r0v.w, m3, a0);
    a1 = fmaf(r1v.x, m0, a1); a1 = fmaf(r1v.y, m1, a1);
    a1 = fmaf(r1v.z, m2, a1); a1 = fmaf(r1v.w, m3, a1);
    a2 = fmaf(r2v.x, m0, a2); a2 = fmaf(r2v.y, m1, a2);
    a2 = fmaf(r2v.z, m2, a2); a2 = fmaf(r2v.w, m3, a2);
    a3 = fmaf(r3v.x, m0, a3); a3 = fmaf(r3v.y, m1, a3);
    a3 = fmaf(r3v.z, m2, a3); a3 = fmaf(r3v.w, m3, a3);
  }

  __shared__ float part[4][4][64];
  part[w][0][lane] = a0;
  part[w][1][lane] = a1;
  part[w][2][lane] = a2;
  part[w][3][lane] = a3;
  __syncthreads();

  if (w == 0) {
    const float f0 = part[0][0][lane] + part[1][0][lane] + part[2][0][lane] + part[3][0][lane];
    const float f1 = part[0][1][lane] + part[1][1][lane] + part[2][1][lane] + part[3][1][lane];
    const float f2 = part[0][2][lane] + part[1][2][lane] + part[2][2][lane] + part[3][2][lane];
    const float f3 = part[0][3][lane] + part[1][3][lane] + part[2][3][lane] + part[3][3][lane];

    float* xy = ws + OFF_X;
    xy[(size_t)(r0 + 0) * DOUT + lane] = f0;
    xy[(size_t)(r0 + 1) * DOUT + lane] = f1;
    xy[(size_t)(r0 + 2) * DOUT + lane] = f2;
    xy[(size_t)(r0 + 3) * DOUT + lane] = f3;

    const float mn4 = fminf(fminf(f0, f1), fminf(f2, f3));
    const float mx4 = fmaxf(fmaxf(f0, f1), fmaxf(f2, f3));
    unsigned* mm = reinterpret_cast<unsigned*>(ws + OFF_MM);
    atomicMin(mm + lane, fkey(mn4));
    atomicMax(mm + 64 + lane, fkey(mx4));

    // row sqnorms n = 0.5||row||^2 -> zpot (tilde of zero potential = -n)
    float n0 = f0 * f0, n1 = f1 * f1, n2 = f2 * f2, n3 = f3 * f3;
#pragma unroll
    for (int off = 32; off > 0; off >>= 1) {
      n0 += __shfl_xor(n0, off, 64);
      n1 += __shfl_xor(n1, off, 64);
      n2 += __shfl_xor(n2, off, 64);
      n3 += __shfl_xor(n3, off, 64);
    }
    if (lane == 0) {
      float* zp = ws + OFF_POTS; // gen 0
      const float nn[4] = {0.5f * n0, 0.5f * n1, 0.5f * n2, 0.5f * n3};
#pragma unroll
      for (int k = 0; k < 4; ++k) {
        const int r = r0 + k;
        if (r < ND) { zp[r] = -nn[k];            zp[3072 + r] = -nn[k]; }
        else        { const int j = r - ND; zp[2048 + j] = -nn[k]; zp[5120 + j] = -nn[k]; }
      }
    }
  }
}

// ---------------- kernel 2: build fp16 dot matrices ----------------
__global__ __launch_bounds__(256) void build_cost(float* __restrict__ ws) {
  const int b = blockIdx.x;
  const int tid = threadIdx.x;

  const float* A;
  const float* B;
  __half* Dout;
  __half* DoutT = nullptr;
  int ldc, ldcT = 0, ti, tj;

  const float* x = ws + OFF_X;
  const float* y = ws + OFF_X + (size_t)ND * DOUT;
  __half* hws = reinterpret_cast<__half*>(ws);

  if (b < 512) {
    ti = b >> 4; tj = b & 15;
    A = x; B = y;
    Dout = hws + H_DXY; ldc = NS;
    DoutT = hws + H_DYX; ldcT = ND;
  } else if (b < 1536) {
    const int bb = b - 512;
    ti = bb >> 5; tj = bb & 31;
    A = x; B = x;
    Dout = hws + H_DXX; ldc = ND;
  } else {
    const int bb = b - 1536;
    ti = bb >> 4; tj = bb & 15;
    A = y; B = y;
    Dout = hws + H_DYY; ldc = NS;
  }

  __shared__ float Ast[64][68];
  __shared__ float Bst[64][68];

  for (int idx = tid; idx < 64 * 16; idx += 256) {
    const int row = idx >> 4;
    const int c4 = idx & 15;
    const float4 a = reinterpret_cast<const float4*>(A + (size_t)(ti * 64 + row) * DOUT)[c4];
    Ast[c4 * 4 + 0][row] = a.x;
    Ast[c4 * 4 + 1][row] = a.y;
    Ast[c4 * 4 + 2][row] = a.z;
    Ast[c4 * 4 + 3][row] = a.w;
    const float4 bv = reinterpret_cast<const float4*>(B + (size_t)(tj * 64 + row) * DOUT)[c4];
    Bst[c4 * 4 + 0][row] = bv.x;
    Bst[c4 * 4 + 1][row] = bv.y;
    Bst[c4 * 4 + 2][row] = bv.z;
    Bst[c4 * 4 + 3][row] = bv.w;
  }
  __syncthreads();

  const int tr = tid >> 4;
  const int tc = tid & 15;
  float acc[4][4] = {};
#pragma unroll 4
  for (int k = 0; k < 64; ++k) {
    float av[4], bv[4];
#pragma unroll
    for (int i = 0; i < 4; ++i) av[i] = Ast[k][tr * 4 + i];
#pragma unroll
    for (int j = 0; j < 4; ++j) bv[j] = Bst[k][tc * 4 + j];
#pragma unroll
    for (int i = 0; i < 4; ++i)
#pragma unroll
      for (int j = 0; j < 4; ++j) acc[i][j] = fmaf(av[i], bv[j], acc[i][j]);
  }

#pragma unroll
  for (int i = 0; i < 4; ++i) {
    const int gi = ti * 64 + tr * 4 + i;
    const int col = tj * 64 + tc * 4;
    const __half h0 = __float2half_rn(acc[i][0]);
    const __half h1 = __float2half_rn(acc[i][1]);
    const __half h2 = __float2half_rn(acc[i][2]);
    const __half h3 = __float2half_rn(acc[i][3]);
    __half2* dst = reinterpret_cast<__half2*>(Dout + (size_t)gi * ldc + col);
    dst[0] = __halves2half2(h0, h1);
    dst[1] = __halves2half2(h2, h3);
    if (DoutT) {
      DoutT[(size_t)(col + 0) * ldcT + gi] = h0;
      DoutT[(size_t)(col + 1) * ldcT + gi] = h1;
      DoutT[(size_t)(col + 2) * ldcT + gi] = h2;
      DoutT[(size_t)(col + 3) * ldcT + gi] = h3;
    }
  }
}

// ---------------- online softmin with REGISTER-RESIDENT dot chunks ----------------
// 8 elems: u = pot + dot(fp16); running (m, s): s = s*2^((m-mn)ie2) + sum 2^((u-mn)ie2)
__device__ inline void chunk_update(const float4 dv, const float4 pa, const float4 pb,
                                    float ie2, float& m, float& s) {
  const __half2* h2 = reinterpret_cast<const __half2*>(&dv);
  const float u0 = pa.x + __low2float(h2[0]), u1 = pa.y + __high2float(h2[0]);
  const float u2 = pa.z + __low2float(h2[1]), u3 = pa.w + __high2float(h2[1]);
  const float u4 = pb.x + __low2float(h2[2]), u5 = pb.y + __high2float(h2[2]);
  const float u6 = pb.z + __low2float(h2[3]), u7 = pb.w + __high2float(h2[3]);
  const float cm = fmaxf(fmaxf(fmaxf(u0, u1), fmaxf(u2, u3)),
                         fmaxf(fmaxf(u4, u5), fmaxf(u6, u7)));
  const float mn = fmaxf(m, cm);
  const float o = -mn * ie2;
  const float p0 = exp2f(fmaf(u0, ie2, o)) + exp2f(fmaf(u1, ie2, o));
  const float p1 = exp2f(fmaf(u2, ie2, o)) + exp2f(fmaf(u3, ie2, o));
  const float p2 = exp2f(fmaf(u4, ie2, o)) + exp2f(fmaf(u5, ie2, o));
  const float p3 = exp2f(fmaf(u6, ie2, o)) + exp2f(fmaf(u7, ie2, o));
  s = fmaf(s, exp2f(fmaf(m, ie2, o)), (p0 + p1) + (p2 + p3));
  m = mn;
}

__device__ inline float softmin_finish(float m, float s, float eps, float ie2,
                                       float log2N) {
  float mw = m;
#pragma unroll
  for (int off = 32; off > 0; off >>= 1) mw = fmaxf(mw, __shfl_xor(mw, off, 64));
  s *= exp2f((m - mw) * ie2);
#pragma unroll
  for (int off = 32; off > 0; off >>= 1) s += __shfl_xor(s, off, 64);
  return -mw - eps * 0.6931471806f * (log2f(s) - log2N);
}

// long job (2048-elem row, dot chunks dv[0..3] in regs); 2 independent chains
__device__ inline float softmin_long(const float4 dv[4],
                                     const float* __restrict__ pt,
                                     int lane, float eps, float ie2) {
  const float4* pf4 = reinterpret_cast<const float4*>(pt);
  float mA = -3.4e38f, sA = 0.f, mB = -3.4e38f, sB = 0.f;
#pragma unroll
  for (int c = 0; c < 2; ++c) {
    const float4 paA = pf4[(2 * c + 0) * 128 + lane * 2];
    const float4 pbA = pf4[(2 * c + 0) * 128 + lane * 2 + 1];
    const float4 paB = pf4[(2 * c + 1) * 128 + lane * 2];
    const float4 pbB = pf4[(2 * c + 1) * 128 + lane * 2 + 1];
    chunk_update(dv[2 * c + 0], paA, pbA, ie2, mA, sA);
    chunk_update(dv[2 * c + 1], paB, pbB, ie2, mB, sB);
  }
  const float mn = fmaxf(mA, mB);
  const float s = fmaf(sA, exp2f((mA - mn) * ie2), sB * exp2f((mB - mn) * ie2));
  return softmin_finish(mn, s, eps, ie2, 11.0f);
}

// dual short jobs (two 1024-elem rows share ONE pot vector): dv[0..1]=row0, dv[2..3]=row1
__device__ inline void softmin_short2(const float4 dv[4],
                                      const float* __restrict__ pt,
                                      int lane, float eps, float ie2,
                                      float& f0, float& f1) {
  const float4* pf4 = reinterpret_cast<const float4*>(pt);
  float m0 = -3.4e38f, s0 = 0.f, m1 = -3.4e38f, s1 = 0.f;
#pragma unroll
  for (int c = 0; c < 2; ++c) {
    const float4 pa = pf4[c * 128 + lane * 2];
    const float4 pb = pf4[c * 128 + lane * 2 + 1];
    chunk_update(dv[c], pa, pb, ie2, m0, s0);
    chunk_update(dv[2 + c], pa, pb, ie2, m1, s1);
  }
  float mw0 = m0, mw1 = m1;
#pragma unroll
  for (int off = 32; off > 0; off >>= 1) {
    mw0 = fmaxf(mw0, __shfl_xor(mw0, off, 64));
    mw1 = fmaxf(mw1, __shfl_xor(mw1, off, 64));
  }
  s0 *= exp2f((m0 - mw0) * ie2);
  s1 *= exp2f((m1 - mw1) * ie2);
#pragma unroll
  for (int off = 32; off > 0; off >>= 1) {
    s0 += __shfl_xor(s0, off, 64);
    s1 += __shfl_xor(s1, off, 64);
  }
  f0 = -mw0 - eps * 0.6931471806f * (log2f(s0) - 10.0f);
  f1 = -mw1 - eps * 0.6931471806f * (log2f(s1) - 10.0f);
}

// ---------------- flat device-wide barrier (2 legs, zero cache-maintenance) -------
// R6..R12 lessons: ACQUIRE polls -> buffer_inv storm (6x slowdown); RELEASE arrivals
// -> buffer_wbl2 per block (~10us/step); per-wave arrivals + detector/fanout chains
// -> regression + livelock risk. This design: block-level RELAXED SYSTEM-scope
// arrival (ordering via __syncthreads' vmcnt(0) drain of the agent-scope pot
// stores), and every block's wave 0 polls the 32 arrival lines DIRECTLY (sum via
// shfl) - no detector, no fanout. Monotone counters, zeroed each launch.
__device__ inline void gbarrier(unsigned* __restrict__ bar, unsigned k) {
  __syncthreads(); // drains vmcnt in all waves: pot stores are at IF$ past here
  if (threadIdx.x == 0)
    __hip_atomic_fetch_add(bar + (size_t)(blockIdx.x & 31) * 64, 1u,
                           __ATOMIC_RELAXED, __HIP_MEMORY_SCOPE_SYSTEM);
  if (threadIdx.x < 64) {
    const unsigned target = 2u * (unsigned)NBLK * k; // each line summed twice (64 lanes, 32 lines)
    for (;;) {
      unsigned sum = __hip_atomic_load(bar + (size_t)(threadIdx.x & 31) * 64,
                                       __ATOMIC_RELAXED, __HIP_MEMORY_SCOPE_SYSTEM);
#pragma unroll
      for (int off = 32; off > 0; off >>= 1)
        sum += (unsigned)__shfl_xor((int)sum, off, 64);
      if (sum >= target) break;
      __builtin_amdgcn_s_sleep(1);
    }
  }
  __syncthreads();
}

// ---------------- kernel 3: fused sinkhorn ----------------
// 1152 blocks x 4 waves = 4608 waves, 2048 elems each, dot rows in registers:
//   W in [0,3072): one LONG row: W<1024 g_ab row W (DYX); else f_aa row W-1024 (DXX).
//   W in [3072,4608): v=W-3072: two SHORT rows k0=2v,k0+1: f_ab (k0<2048) or g_bb.
__global__ __launch_bounds__(256, 6) void sinkhorn_fused(float* __restrict__ ws,
                                                         float* __restrict__ out) {
  const int w    = threadIdx.x >> 6;
  const int lane = threadIdx.x & 63;
  const int W    = blockIdx.x * 4 + w;
  float* pots = ws + OFF_POTS;
  unsigned* bar = reinterpret_cast<unsigned*>(ws + OFF_BARRIER);
  const __half* hws = reinterpret_cast<const __half*>(ws);

  // diameter^2 from mm keys
  float diam2;
  {
    const unsigned* mm = reinterpret_cast<const unsigned*>(ws + OFF_MM);
    const float mn = funkey(mm[lane]);
    const float mx = funkey(mm[64 + lane]);
    const float rng = mx - mn;
    float p = rng * rng;
#pragma unroll
    for (int off = 32; off > 0; off >>= 1) p += __shfl_xor(p, off, 64);
    diam2 = p;
  }

  // static per-wave geometry
  const bool isLong = (W < 3072);
  const bool isGab  = (W < 1024);
  int ptOff = 0, out0 = 0, out1 = -1;
  const __half* Dr0 = nullptr;
  const __half* Dr1 = nullptr;
  if (isLong) {
    if (isGab) { Dr0 = hws + H_DYX + (size_t)W * ND;          ptOff = 0;    }
    else       { Dr0 = hws + H_DXX + (size_t)(W - 1024) * ND; ptOff = 3072; }
    out0 = 2048 + W;
  } else {
    const int v = W - 3072;
    const int k0 = 2 * v;
    if (k0 < 2048) { Dr0 = hws + H_DXY + (size_t)k0 * NS; Dr1 = Dr0 + NS;
                     ptOff = 2048; out0 = k0; out1 = k0 + 1; }
    else { const int r = k0 - 2048; Dr0 = hws + H_DYY + (size_t)r * NS; Dr1 = Dr0 + NS;
           ptOff = 5120; out0 = 5120 + r; out1 = out0 + 1; }
  }

  // ---- preload dot rows into registers: CONSTANT across all 22 steps
  float4 dv[4];
  if (isLong) {
    const float4* df4 = reinterpret_cast<const float4*>(Dr0);
#pragma unroll
    for (int c = 0; c < 4; ++c) dv[c] = df4[c * 64 + lane];
  } else {
    const float4* d0 = reinterpret_cast<const float4*>(Dr0);
    const float4* d1 = reinterpret_cast<const float4*>(Dr1);
#pragma unroll
    for (int c = 0; c < 2; ++c) { dv[c] = d0[c * 64 + lane]; dv[2 + c] = d1[c * 64 + lane]; }
  }

  unsigned bk = 0;

  auto doStep = [&](const float* pin, float* pout, float eps, float ie2, bool avg) {
    if (isLong) {
      const float prev = avg ? pin[out0] : 0.f;
      float f = softmin_long(dv, pin + ptOff, lane, eps, ie2);
      if (avg) f = 0.5f * (prev + f);
      if (lane == 0)
        __hip_atomic_store(&pout[out0], f, __ATOMIC_RELAXED, __HIP_MEMORY_SCOPE_AGENT);
    } else {
      const float prev0 = avg ? pin[out0] : 0.f;
      const float prev1 = avg ? pin[out1] : 0.f;
      float f0, f1;
      softmin_short2(dv, pin + ptOff, lane, eps, ie2, f0, f1);
      if (avg) { f0 = 0.5f * (prev0 + f0); f1 = 0.5f * (prev1 + f1); }
      if (lane == 0) {
        __hip_atomic_store(&pout[out0], f0, __ATOMIC_RELAXED, __HIP_MEMORY_SCOPE_AGENT);
        __hip_atomic_store(&pout[out1], f1, __ATOMIC_RELAXED, __HIP_MEMORY_SCOPE_AGENT);
      }
    }
  };

  // ---- init (pin = gen0 = -n, no avg) + 20 averaged steps
  for (int t = -1; t < NSTEPS; ++t) {
    const float eps = (t < 0) ? fmaxf(diam2, BLUR2)
                              : fmaxf(ldexpf(diam2, -2 * t), BLUR2);
    const float ie2 = 1.4426950409f / eps;
    const float* pin  = pots + (size_t)(t + 1) * POT_STRIDE;
    float*       pout = pots + (size_t)(t + 2) * POT_STRIDE;
    doStep(pin, pout, eps, ie2, t >= 0);
    gbarrier(bar, ++bk);
  }

  // ---- final extrapolation at eps = blur^2: gen21 -> gen22
  {
    const float eps = BLUR2;
    const float ie2 = 1.4426950409f / eps;
    const float* pin  = pots + (size_t)(NSTEPS + 1) * POT_STRIDE; // gen21
    float*       pout = pots + (size_t)(NSTEPS + 2) * POT_STRIDE; // gen22
    // phase A: f_ab, f_aa, g_bb (g_ab waves idle)
    if (!isGab) doStep(pin, pout, eps, ie2, false);
    gbarrier(bar, ++bk);
    // phase B: g_ab from the NEW f~_ab (gen22 in/out)
    if (isGab) doStep(pout, pout, eps, ie2, false);
    gbarrier(bar, ++bk);
  }

  // ---- epilogue (tilde cancels in the differences)
  if (blockIdx.x == 0) {
    const float* pot = pots + (size_t)(NSTEPS + 2) * POT_STRIDE;
    const int tid = threadIdx.x;
    float s1 = 0.f, s2 = 0.f;
    for (int i = tid; i < ND; i += 256) s1 += pot[i] - pot[3072 + i];
    for (int j = tid; j < NS; j += 256) s2 += pot[2048 + j] - pot[5120 + j];
    float part = s1 * (1.0f / (float)ND) + s2 * (1.0f / (float)NS);
#pragma unroll
    for (int off = 32; off > 0; off >>= 1) part += __shfl_xor(part, off, 64);
    __shared__ float sp[4];
    if ((tid & 63) == 0) sp[tid >> 6] = part;
    __syncthreads();
    if (tid == 0) out[0] = expf(-(sp[0] + sp[1] + sp[2] + sp[3]));
  }
}

// ---------------- host ----------------
extern "C" void kernel_launch(void* const* d_in, const int* in_sizes, int n_in,
                              void* d_out, int out_size, void* d_ws, size_t ws_size,
                              hipStream_t stream) {
  const float* d = (const float*)d_in[0];
  const float* s = (const float*)d_in[1];
  const float* M = (const float*)d_in[2];
  float* out = (float*)d_out;
  float* ws = (float*)d_ws;

  init_mm<<<1, 256, 0, stream>>>(ws);
  proj_kernel<<<768, 256, 0, stream>>>(d, s, M, ws);
  build_cost<<<1792, 256, 0, stream>>>(ws);
  sinkhorn_fused<<<NBLK, 256, 0, stream>>>(ws, out);
}

// Round 14
// 210.222 us; speedup vs baseline: 1.8389x; 1.8389x over previous
//
#include <hip/hip_runtime.h>
#include <hip/hip_fp16.h>
#include <math.h>

// ---------------- problem constants ----------------
#define ND 2048
#define NS 1024
#define DIN 768
#define DOUT 64
#define NSTEPS 20
static constexpr float BLUR2 = 0.05f * 0.05f; // blur^p, p=2

// ---------------- ws layout ----------------
// float offsets:
#define OFF_X     0u              // 3072*64 = 196608
#define OFF_MM    199680u         // 128 uints: 64 min keys | 64 max keys
#define OFF_POTS  199808u         // 23 gens x 6144 floats (TILDE potentials p~ = p - n)
                                  // gen0 = zpot (-n), gen1 = init, gen2..21 = steps,
                                  // gen22 = final. per gen:
                                  // [f_ab 2048 | g_ab 1024 | f_aa 2048 | g_bb 1024]
#define POT_STRIDE 6144u
#define OFF_BARRIER 341120u       // 6144 uints: 64 arrival lines + 32 gen lines
// half offsets (element index into (__half*)ws): fp16 dot matrices
#define H_DXY 694528u             // 2048x1024
#define H_DYX 2791680u            // 1024x2048 (transpose)
#define H_DXX 4888832u            // 2048x2048
#define H_DYY 9083136u            // 1024x1024

// 1152 blocks = 4.5 blocks/CU. __launch_bounds__(256,6) -> HW capacity 6 blocks/CU
// > 4.5 needed: co-residency margin for the device barrier.
#define NBLK 1152

// monotone float<->uint key encoding (order-preserving for atomicMin/Max)
__device__ inline unsigned fkey(float f) {
  const unsigned b = __float_as_uint(f);
  return (b & 0x80000000u) ? ~b : (b | 0x80000000u);
}
__device__ inline float funkey(unsigned k) {
  const unsigned b = (k & 0x80000000u) ? (k & 0x7FFFFFFFu) : ~k;
  return __uint_as_float(b);
}

// ---------------- kernel 0: seed min/max keys + zero barrier area ----------------
__global__ __launch_bounds__(256) void init_mm(float* __restrict__ ws) {
  const int t = threadIdx.x;
  unsigned* mm = reinterpret_cast<unsigned*>(ws + OFF_MM);
  if (t < 64)       mm[t] = 0xFFFFFFFFu;
  else if (t < 128) mm[t] = 0u;
  unsigned* bar = reinterpret_cast<unsigned*>(ws + OFF_BARRIER);
  for (int i = t; i < 6144; i += 256) bar[i] = 0u;
}

// ---------------- kernel 1: projection (K-split) + zpot + atomic min/max ----------
__global__ __launch_bounds__(256) void proj_kernel(const float* __restrict__ d,
                                                   const float* __restrict__ s,
                                                   const float* __restrict__ M,
                                                   float* __restrict__ ws) {
  const int w    = threadIdx.x >> 6;
  const int lane = threadIdx.x & 63;
  const int r0   = blockIdx.x * 4;

  const float* base;
  if (r0 < ND) base = d + (size_t)r0 * DIN;
  else         base = s + (size_t)(r0 - ND) * DIN;

  const float4* s0 = reinterpret_cast<const float4*>(base + 0 * DIN + w * 192);
  const float4* s1 = reinterpret_cast<const float4*>(base + 1 * DIN + w * 192);
  const float4* s2 = reinterpret_cast<const float4*>(base + 2 * DIN + w * 192);
  const float4* s3 = reinterpret_cast<const float4*>(base + 3 * DIN + w * 192);
  const float* Mw = M + (size_t)(w * 192) * DOUT + lane;

  float a0 = 0.f, a1 = 0.f, a2 = 0.f, a3 = 0.f;
#pragma unroll 4
  for (int kk = 0; kk < 48; ++kk) {
    const float4 r0v = s0[kk];
    const float4 r1v = s1[kk];
    const float4 r2v = s2[kk];
    const float4 r3v = s3[kk];
    const float m0 = Mw[(kk * 4 + 0) * DOUT];
    const float m1 = Mw[(kk * 4 + 1) * DOUT];
    const float m2 = Mw[(kk * 4 + 2) * DOUT];
    const float m3 = Mw[(kk * 4 + 3) * DOUT];
    a0 = fmaf(r0v.x, m0, a0); a0 = fmaf(r0v.y, m1, a0);
    a0 = fmaf(r0v.z, m2, a0); a0 = fmaf(r0v.w, m3, a0);
    a1 = fmaf(r1v.x, m0, a1); a1 = fmaf(r1v.y, m1, a1);
    a1 = fmaf(r1v.z, m2, a1); a1 = fmaf(r1v.w, m3, a1);
    a2 = fmaf(r2v.x, m0, a2); a2 = fmaf(r2v.y, m1, a2);
    a2 = fmaf(r2v.z, m2, a2); a2 = fmaf(r2v.w, m3, a2);
    a3 = fmaf(r3v.x, m0, a3); a3 = fmaf(r3v.y, m1, a3);
    a3 = fmaf(r3v.z, m2, a3); a3 = fmaf(r3v.w, m3, a3);
  }

  __shared__ float part[4][4][64];
  part[w][0][lane] = a0;
  part[w][1][lane] = a1;
  part[w][2][lane] = a2;
  part[w][3][lane] = a3;
  __syncthreads();

  if (w == 0) {
    const float f0 = part[0][0][lane] + part[1][0][lane] + part[2][0][lane] + part[3][0][lane];
    const float f1 = part[0][1][lane] + part[1][1][lane] + part[2][1][lane] + part[3][1][lane];
    const float f2 = part[0][2][lane] + part[1][2][lane] + part[2][2][lane] + part[3][2][lane];
    const float f3 = part[0][3][lane] + part[1][3][lane] + part[2][3][lane] + part[3][3][lane];

    float* xy = ws + OFF_X;
    xy[(size_t)(r0 + 0) * DOUT + lane] = f0;
    xy[(size_t)(r0 + 1) * DOUT + lane] = f1;
    xy[(size_t)(r0 + 2) * DOUT + lane] = f2;
    xy[(size_t)(r0 + 3) * DOUT + lane] = f3;

    const float mn4 = fminf(fminf(f0, f1), fminf(f2, f3));
    const float mx4 = fmaxf(fmaxf(f0, f1), fmaxf(f2, f3));
    unsigned* mm = reinterpret_cast<unsigned*>(ws + OFF_MM);
    atomicMin(mm + lane, fkey(mn4));
    atomicMax(mm + 64 + lane, fkey(mx4));

    // row sqnorms n = 0.5||row||^2 -> zpot (tilde of zero potential = -n)
    float n0 = f0 * f0, n1 = f1 * f1, n2 = f2 * f2, n3 = f3 * f3;
#pragma unroll
    for (int off = 32; off > 0; off >>= 1) {
      n0 += __shfl_xor(n0, off, 64);
      n1 += __shfl_xor(n1, off, 64);
      n2 += __shfl_xor(n2, off, 64);
      n3 += __shfl_xor(n3, off, 64);
    }
    if (lane == 0) {
      float* zp = ws + OFF_POTS; // gen 0
      const float nn[4] = {0.5f * n0, 0.5f * n1, 0.5f * n2, 0.5f * n3};
#pragma unroll
      for (int k = 0; k < 4; ++k) {
        const int r = r0 + k;
        if (r < ND) { zp[r] = -nn[k];            zp[3072 + r] = -nn[k]; }
        else        { const int j = r - ND; zp[2048 + j] = -nn[k]; zp[5120 + j] = -nn[k]; }
      }
    }
  }
}

// ---------------- kernel 2: build fp16 dot matrices ----------------
__global__ __launch_bounds__(256) void build_cost(float* __restrict__ ws) {
  const int b = blockIdx.x;
  const int tid = threadIdx.x;

  const float* A;
  const float* B;
  __half* Dout;
  __half* DoutT = nullptr;
  int ldc, ldcT = 0, ti, tj;

  const float* x = ws + OFF_X;
  const float* y = ws + OFF_X + (size_t)ND * DOUT;
  __half* hws = reinterpret_cast<__half*>(ws);

  if (b < 512) {
    ti = b >> 4; tj = b & 15;
    A = x; B = y;
    Dout = hws + H_DXY; ldc = NS;
    DoutT = hws + H_DYX; ldcT = ND;
  } else if (b < 1536) {
    const int bb = b - 512;
    ti = bb >> 5; tj = bb & 31;
    A = x; B = x;
    Dout = hws + H_DXX; ldc = ND;
  } else {
    const int bb = b - 1536;
    ti = bb >> 4; tj = bb & 15;
    A = y; B = y;
    Dout = hws + H_DYY; ldc = NS;
  }

  __shared__ float Ast[64][68];
  __shared__ float Bst[64][68];

  for (int idx = tid; idx < 64 * 16; idx += 256) {
    const int row = idx >> 4;
    const int c4 = idx & 15;
    const float4 a = reinterpret_cast<const float4*>(A + (size_t)(ti * 64 + row) * DOUT)[c4];
    Ast[c4 * 4 + 0][row] = a.x;
    Ast[c4 * 4 + 1][row] = a.y;
    Ast[c4 * 4 + 2][row] = a.z;
    Ast[c4 * 4 + 3][row] = a.w;
    const float4 bv = reinterpret_cast<const float4*>(B + (size_t)(tj * 64 + row) * DOUT)[c4];
    Bst[c4 * 4 + 0][row] = bv.x;
    Bst[c4 * 4 + 1][row] = bv.y;
    Bst[c4 * 4 + 2][row] = bv.z;
    Bst[c4 * 4 + 3][row] = bv.w;
  }
  __syncthreads();

  const int tr = tid >> 4;
  const int tc = tid & 15;
  float acc[4][4] = {};
#pragma unroll 4
  for (int k = 0; k < 64; ++k) {
    float av[4], bv[4];
#pragma unroll
    for (int i = 0; i < 4; ++i) av[i] = Ast[k][tr * 4 + i];
#pragma unroll
    for (int j = 0; j < 4; ++j) bv[j] = Bst[k][tc * 4 + j];
#pragma unroll
    for (int i = 0; i < 4; ++i)
#pragma unroll
      for (int j = 0; j < 4; ++j) acc[i][j] = fmaf(av[i], bv[j], acc[i][j]);
  }

#pragma unroll
  for (int i = 0; i < 4; ++i) {
    const int gi = ti * 64 + tr * 4 + i;
    const int col = tj * 64 + tc * 4;
    const __half h0 = __float2half_rn(acc[i][0]);
    const __half h1 = __float2half_rn(acc[i][1]);
    const __half h2 = __float2half_rn(acc[i][2]);
    const __half h3 = __float2half_rn(acc[i][3]);
    __half2* dst = reinterpret_cast<__half2*>(Dout + (size_t)gi * ldc + col);
    dst[0] = __halves2half2(h0, h1);
    dst[1] = __halves2half2(h2, h3);
    if (DoutT) {
      DoutT[(size_t)(col + 0) * ldcT + gi] = h0;
      DoutT[(size_t)(col + 1) * ldcT + gi] = h1;
      DoutT[(size_t)(col + 2) * ldcT + gi] = h2;
      DoutT[(size_t)(col + 3) * ldcT + gi] = h3;
    }
  }
}

// ---------------- online softmin with REGISTER-RESIDENT dot chunks ----------------
// 8 elems: u = pot + dot(fp16); running (m, s): s = s*2^((m-mn)ie2) + sum 2^((u-mn)ie2)
__device__ inline void chunk_update(const float4 dv, const float4 pa, const float4 pb,
                                    float ie2, float& m, float& s) {
  const __half2* h2 = reinterpret_cast<const __half2*>(&dv);
  const float u0 = pa.x + __low2float(h2[0]), u1 = pa.y + __high2float(h2[0]);
  const float u2 = pa.z + __low2float(h2[1]), u3 = pa.w + __high2float(h2[1]);
  const float u4 = pb.x + __low2float(h2[2]), u5 = pb.y + __high2float(h2[2]);
  const float u6 = pb.z + __low2float(h2[3]), u7 = pb.w + __high2float(h2[3]);
  const float cm = fmaxf(fmaxf(fmaxf(u0, u1), fmaxf(u2, u3)),
                         fmaxf(fmaxf(u4, u5), fmaxf(u6, u7)));
  const float mn = fmaxf(m, cm);
  const float o = -mn * ie2;
  const float p0 = exp2f(fmaf(u0, ie2, o)) + exp2f(fmaf(u1, ie2, o));
  const float p1 = exp2f(fmaf(u2, ie2, o)) + exp2f(fmaf(u3, ie2, o));
  const float p2 = exp2f(fmaf(u4, ie2, o)) + exp2f(fmaf(u5, ie2, o));
  const float p3 = exp2f(fmaf(u6, ie2, o)) + exp2f(fmaf(u7, ie2, o));
  s = fmaf(s, exp2f(fmaf(m, ie2, o)), (p0 + p1) + (p2 + p3));
  m = mn;
}

__device__ inline float softmin_finish(float m, float s, float eps, float ie2,
                                       float log2N) {
  float mw = m;
#pragma unroll
  for (int off = 32; off > 0; off >>= 1) mw = fmaxf(mw, __shfl_xor(mw, off, 64));
  s *= exp2f((m - mw) * ie2);
#pragma unroll
  for (int off = 32; off > 0; off >>= 1) s += __shfl_xor(s, off, 64);
  return -mw - eps * 0.6931471806f * (log2f(s) - log2N);
}

// long job (2048-elem row, dot chunks dv[0..3] in regs); 2 independent chains
__device__ inline float softmin_long(const float4 dv[4],
                                     const float* __restrict__ pt,
                                     int lane, float eps, float ie2) {
  const float4* pf4 = reinterpret_cast<const float4*>(pt);
  float mA = -3.4e38f, sA = 0.f, mB = -3.4e38f, sB = 0.f;
#pragma unroll
  for (int c = 0; c < 2; ++c) {
    const float4 paA = pf4[(2 * c + 0) * 128 + lane * 2];
    const float4 pbA = pf4[(2 * c + 0) * 128 + lane * 2 + 1];
    const float4 paB = pf4[(2 * c + 1) * 128 + lane * 2];
    const float4 pbB = pf4[(2 * c + 1) * 128 + lane * 2 + 1];
    chunk_update(dv[2 * c + 0], paA, pbA, ie2, mA, sA);
    chunk_update(dv[2 * c + 1], paB, pbB, ie2, mB, sB);
  }
  const float mn = fmaxf(mA, mB);
  const float s = fmaf(sA, exp2f((mA - mn) * ie2), sB * exp2f((mB - mn) * ie2));
  return softmin_finish(mn, s, eps, ie2, 11.0f);
}

// dual short jobs (two 1024-elem rows share ONE pot vector): dv[0..1]=row0, dv[2..3]=row1
__device__ inline void softmin_short2(const float4 dv[4],
                                      const float* __restrict__ pt,
                                      int lane, float eps, float ie2,
                                      float& f0, float& f1) {
  const float4* pf4 = reinterpret_cast<const float4*>(pt);
  float m0 = -3.4e38f, s0 = 0.f, m1 = -3.4e38f, s1 = 0.f;
#pragma unroll
  for (int c = 0; c < 2; ++c) {
    const float4 pa = pf4[c * 128 + lane * 2];
    const float4 pb = pf4[c * 128 + lane * 2 + 1];
    chunk_update(dv[c], pa, pb, ie2, m0, s0);
    chunk_update(dv[2 + c], pa, pb, ie2, m1, s1);
  }
  float mw0 = m0, mw1 = m1;
#pragma unroll
  for (int off = 32; off > 0; off >>= 1) {
    mw0 = fmaxf(mw0, __shfl_xor(mw0, off, 64));
    mw1 = fmaxf(mw1, __shfl_xor(mw1, off, 64));
  }
  s0 *= exp2f((m0 - mw0) * ie2);
  s1 *= exp2f((m1 - mw1) * ie2);
#pragma unroll
  for (int off = 32; off > 0; off >>= 1) {
    s0 += __shfl_xor(s0, off, 64);
    s1 += __shfl_xor(s1, off, 64);
  }
  f0 = -mw0 - eps * 0.6931471806f * (log2f(s0) - 10.0f);
  f1 = -mw1 - eps * 0.6931471806f * (log2f(s1) - 10.0f);
}

// ---------------- device-wide barrier (R11 hierarchical, proven 166us config) -----
// ZERO cache-maintenance ops:
//  * R6: ACQUIRE polls -> buffer_inv storm (6x slowdown).
//  * R7-10: RELEASE arrival fetch_add -> buffer_wbl2 per block (~10us/step).
//  * R12: per-wave arrivals + dual detector chains -> regression + livelock risk.
//  * R13: all-blocks-poll on 32 shared lines -> IF$ contention (2300 loads/line/iter)
//    -> 2x regression. Hierarchical polling (detector wave + fanout) keeps per-line
//    traffic ~36 loads/iter.
//  * Ordering is free: __syncthreads() drains vmcnt(0) in every wave, so the
//    agent-scope pot stores are at IF$ before thread 0 issues the arrival add.
//  * All ops RELAXED SYSTEM scope (sc0+sc1): execute at IF$, always fresh.
__device__ inline void gbarrier(unsigned* __restrict__ bar, unsigned k) {
  __syncthreads(); // drains vmcnt in all waves: pot stores are at IF$ past here
  if (threadIdx.x == 0) {
    unsigned* cnt = bar + (size_t)(blockIdx.x & 63) * 64;
    __hip_atomic_fetch_add(cnt, 1u, __ATOMIC_RELAXED, __HIP_MEMORY_SCOPE_SYSTEM);
  }
  if (blockIdx.x == 0) {
    if (threadIdx.x < 64) {
      const unsigned target = (unsigned)NBLK * k;
      for (;;) {
        unsigned sum = __hip_atomic_load(bar + (size_t)threadIdx.x * 64,
                                         __ATOMIC_RELAXED, __HIP_MEMORY_SCOPE_SYSTEM);
#pragma unroll
        for (int off = 32; off > 0; off >>= 1)
          sum += (unsigned)__shfl_xor((int)sum, off, 64);
        if (sum >= target) break;
        __builtin_amdgcn_s_sleep(2);
      }
      if (threadIdx.x < 32)
        __hip_atomic_store(bar + 4096 + (size_t)threadIdx.x * 64, k,
                           __ATOMIC_RELAXED, __HIP_MEMORY_SCOPE_SYSTEM);
    }
  } else {
    if (threadIdx.x == 0) {
      while (__hip_atomic_load(bar + 4096 + (size_t)(blockIdx.x & 31) * 64,
                               __ATOMIC_RELAXED, __HIP_MEMORY_SCOPE_SYSTEM) < k)
        __builtin_amdgcn_s_sleep(2);
    }
  }
  __syncthreads();
}

// ---------------- kernel 3: fused sinkhorn ----------------
// 1152 blocks x 4 waves = 4608 waves, 2048 elems each, dot rows in REGISTERS:
//   W in [0,3072): one LONG row: W<1024 g_ab row W (DYX); else f_aa row W-1024 (DXX).
//   W in [3072,4608): v=W-3072: two SHORT rows k0=2v,k0+1: f_ab (k0<2048) or g_bb.
__global__ __launch_bounds__(256, 6) void sinkhorn_fused(float* __restrict__ ws,
                                                         float* __restrict__ out) {
  const int w    = threadIdx.x >> 6;
  const int lane = threadIdx.x & 63;
  const int W    = blockIdx.x * 4 + w;
  float* pots = ws + OFF_POTS;
  unsigned* bar = reinterpret_cast<unsigned*>(ws + OFF_BARRIER);
  const __half* hws = reinterpret_cast<const __half*>(ws);

  // diameter^2 from mm keys
  float diam2;
  {
    const unsigned* mm = reinterpret_cast<const unsigned*>(ws + OFF_MM);
    const float mn = funkey(mm[lane]);
    const float mx = funkey(mm[64 + lane]);
    const float rng = mx - mn;
    float p = rng * rng;
#pragma unroll
    for (int off = 32; off > 0; off >>= 1) p += __shfl_xor(p, off, 64);
    diam2 = p;
  }

  // static per-wave geometry
  const bool isLong = (W < 3072);
  const bool isGab  = (W < 1024);
  int ptOff = 0, out0 = 0, out1 = -1;
  const __half* Dr0 = nullptr;
  const __half* Dr1 = nullptr;
  if (isLong) {
    if (isGab) { Dr0 = hws + H_DYX + (size_t)W * ND;          ptOff = 0;    }
    else       { Dr0 = hws + H_DXX + (size_t)(W - 1024) * ND; ptOff = 3072; }
    out0 = 2048 + W;
  } else {
    const int v = W - 3072;
    const int k0 = 2 * v;
    if (k0 < 2048) { Dr0 = hws + H_DXY + (size_t)k0 * NS; Dr1 = Dr0 + NS;
                     ptOff = 2048; out0 = k0; out1 = k0 + 1; }
    else { const int r = k0 - 2048; Dr0 = hws + H_DYY + (size_t)r * NS; Dr1 = Dr0 + NS;
           ptOff = 5120; out0 = 5120 + r; out1 = out0 + 1; }
  }

  // ---- preload dot rows into registers: CONSTANT across all 22 steps
  float4 dv[4];
  if (isLong) {
    const float4* df4 = reinterpret_cast<const float4*>(Dr0);
#pragma unroll
    for (int c = 0; c < 4; ++c) dv[c] = df4[c * 64 + lane];
  } else {
    const float4* d0 = reinterpret_cast<const float4*>(Dr0);
    const float4* d1 = reinterpret_cast<const float4*>(Dr1);
#pragma unroll
    for (int c = 0; c < 2; ++c) { dv[c] = d0[c * 64 + lane]; dv[2 + c] = d1[c * 64 + lane]; }
  }

  unsigned bk = 0;

  auto doStep = [&](const float* pin, float* pout, float eps, float ie2, bool avg) {
    if (isLong) {
      const float prev = avg ? pin[out0] : 0.f;
      float f = softmin_long(dv, pin + ptOff, lane, eps, ie2);
      if (avg) f = 0.5f * (prev + f);
      if (lane == 0)
        __hip_atomic_store(&pout[out0], f, __ATOMIC_RELAXED, __HIP_MEMORY_SCOPE_AGENT);
    } else {
      const float prev0 = avg ? pin[out0] : 0.f;
      const float prev1 = avg ? pin[out1] : 0.f;
      float f0, f1;
      softmin_short2(dv, pin + ptOff, lane, eps, ie2, f0, f1);
      if (avg) { f0 = 0.5f * (prev0 + f0); f1 = 0.5f * (prev1 + f1); }
      if (lane == 0) {
        __hip_atomic_store(&pout[out0], f0, __ATOMIC_RELAXED, __HIP_MEMORY_SCOPE_AGENT);
        __hip_atomic_store(&pout[out1], f1, __ATOMIC_RELAXED, __HIP_MEMORY_SCOPE_AGENT);
      }
    }
  };

  // ---- init (pin = gen0 = -n, no avg) + 20 averaged steps
  for (int t = -1; t < NSTEPS; ++t) {
    const float eps = (t < 0) ? fmaxf(diam2, BLUR2)
                              : fmaxf(ldexpf(diam2, -2 * t), BLUR2);
    const float ie2 = 1.4426950409f / eps;
    const float* pin  = pots + (size_t)(t + 1) * POT_STRIDE;
    float*       pout = pots + (size_t)(t + 2) * POT_STRIDE;
    doStep(pin, pout, eps, ie2, t >= 0);
    gbarrier(bar, ++bk);
  }

  // ---- final extrapolation at eps = blur^2: gen21 -> gen22
  {
    const float eps = BLUR2;
    const float ie2 = 1.4426950409f / eps;
    const float* pin  = pots + (size_t)(NSTEPS + 1) * POT_STRIDE; // gen21
    float*       pout = pots + (size_t)(NSTEPS + 2) * POT_STRIDE; // gen22
    // phase A: f_ab, f_aa, g_bb (g_ab waves idle)
    if (!isGab) doStep(pin, pout, eps, ie2, false);
    gbarrier(bar, ++bk);
    // phase B: g_ab from the NEW f~_ab (gen22 in/out)
    if (isGab) doStep(pout, pout, eps, ie2, false);
    gbarrier(bar, ++bk);
  }

  // ---- epilogue (tilde cancels in the differences)
  if (blockIdx.x == 0) {
    const float* pot = pots + (size_t)(NSTEPS + 2) * POT_STRIDE;
    const int tid = threadIdx.x;
    float s1 = 0.f, s2 = 0.f;
    for (int i = tid; i < ND; i += 256) s1 += pot[i] - pot[3072 + i];
    for (int j = tid; j < NS; j += 256) s2 += pot[2048 + j] - pot[5120 + j];
    float part = s1 * (1.0f / (float)ND) + s2 * (1.0f / (float)NS);
#pragma unroll
    for (int off = 32; off > 0; off >>= 1) part += __shfl_xor(part, off, 64);
    __shared__ float sp[4];
    if ((tid & 63) == 0) sp[tid >> 6] = part;
    __syncthreads();
    if (tid == 0) out[0] = expf(-(sp[0] + sp[1] + sp[2] + sp[3]));
  }
}

// ---------------- host ----------------
extern "C" void kernel_launch(void* const* d_in, const int* in_sizes, int n_in,
                              void* d_out, int out_size, void* d_ws, size_t ws_size,
                              hipStream_t stream) {
  const float* d = (const float*)d_in[0];
  const float* s = (const float*)d_in[1];
  const float* M = (const float*)d_in[2];
  float* out = (float*)d_out;
  float* ws = (float*)d_ws;

  init_mm<<<1, 256, 0, stream>>>(ws);
  proj_kernel<<<768, 256, 0, stream>>>(d, s, M, ws);
  build_cost<<<1792, 256, 0, stream>>>(ws);
  sinkhorn_fused<<<NBLK, 256, 0, stream>>>(ws, out);
}